// Round 2
// baseline (623.008 us; speedup 1.0000x reference)
//
#include <hip/hip_runtime.h>

// PointPillarScatter, slot-major gather formulation:
//   pass 1: winner[b*SS + s] = max p scattering into (b,s)   (last-write-wins)
//   pass 2: one thread per slot reads winner once, streams the pillar's
//           64-float row contiguously, writes 64 channels at stride SS.
// SS is divisible by 256 -> b and store bases are wave-uniform; per-channel
// stores are 64 lanes x 4B consecutive = fully coalesced 256B lines.

#define NXx 432
#define NYy 496
#define SS  (NXx * NYy)   // 214272, divisible by 256
#define CC  64

__global__ void winner_kernel(const int* __restrict__ cb,
                              const int* __restrict__ cz,
                              const int* __restrict__ cy,
                              const int* __restrict__ cx,
                              int* __restrict__ winner, int P) {
    int p = blockIdx.x * blockDim.x + threadIdx.x;
    if (p < P) {
        int slot = cb[p] * SS + cz[p] + cy[p] * NXx + cx[p];
        atomicMax(&winner[slot], p);   // last (max p) wins — verified vs ref in R1
    }
}

__global__ void scatter_kernel(const float* __restrict__ pf,
                               const int* __restrict__ winner,
                               float* __restrict__ out, int nslots) {
    int slot = blockIdx.x * blockDim.x + threadIdx.x;
    if (slot >= nslots) return;
    int w = winner[slot];              // read exactly once per slot
    int b = slot / SS;                 // magic-mul const divide
    int s = slot - b * SS;
    float* obase = out + (size_t)b * (CC * SS) + s;
    if (w >= 0) {
        const float4* prow = reinterpret_cast<const float4*>(pf + (size_t)w * CC);
        #pragma unroll
        for (int q = 0; q < CC / 4; ++q) {
            float4 v = prow[q];        // contiguous 16B of the pillar row
            obase[(size_t)(4 * q + 0) * SS] = v.x;
            obase[(size_t)(4 * q + 1) * SS] = v.y;
            obase[(size_t)(4 * q + 2) * SS] = v.z;
            obase[(size_t)(4 * q + 3) * SS] = v.w;
        }
    } else {
        #pragma unroll
        for (int c = 0; c < CC; ++c)
            obase[(size_t)c * SS] = 0.0f;   // fused zero-fill
    }
}

extern "C" void kernel_launch(void* const* d_in, const int* in_sizes, int n_in,
                              void* d_out, int out_size, void* d_ws, size_t ws_size,
                              hipStream_t stream) {
    const float* pf = (const float*)d_in[0];
    const int* cb   = (const int*)d_in[1];
    const int* cz   = (const int*)d_in[2];
    const int* cy   = (const int*)d_in[3];
    const int* cx   = (const int*)d_in[4];
    float* out      = (float*)d_out;

    const int P      = in_sizes[1];            // number of pillars
    const int nslots = out_size / CC;          // B * SS = 1,714,176

    int* winner = (int*)d_ws;                  // nslots ints = 6.86 MB
    hipMemsetAsync(winner, 0xFF, (size_t)nslots * sizeof(int), stream);  // -1

    winner_kernel<<<(P + 255) / 256, 256, 0, stream>>>(cb, cz, cy, cx, winner, P);

    scatter_kernel<<<(nslots + 255) / 256, 256, 0, stream>>>(pf, winner, out, nslots);
}

// Round 3
// 558.024 us; speedup vs baseline: 1.1165x; 1.1165x over previous
//
#include <hip/hip_runtime.h>

// PointPillarScatter, branchless slot-major scatter:
//   pass 1: winner[b*SS+s] = max p writing (b,s)   (last-write-wins, verified R1)
//   pass 2: each thread owns 4 consecutive slots; reads winner int4, streams the
//           4 pillar rows contiguously (256B each), transposes 4x4 in registers,
//           stores float4 per channel -> every wave store = 1KB contiguous,
//           all lanes active (empty slots use row 0 scaled by 0).

#define NXx 432
#define NYy 496
#define SS  (NXx * NYy)   // 214272, divisible by 256
#define CC  64

__global__ void winner_kernel(const int* __restrict__ cb,
                              const int* __restrict__ cz,
                              const int* __restrict__ cy,
                              const int* __restrict__ cx,
                              int* __restrict__ winner, int P) {
    int p = blockIdx.x * blockDim.x + threadIdx.x;
    if (p < P) {
        int slot = cb[p] * SS + cz[p] + cy[p] * NXx + cx[p];
        atomicMax(&winner[slot], p);
    }
}

__global__ void scatter_kernel(const float* __restrict__ pf,
                               const int* __restrict__ winner,
                               float* __restrict__ out, int ngroups) {
    int g = blockIdx.x * blockDim.x + threadIdx.x;
    if (g >= ngroups) return;
    int slot0 = g << 2;                 // 4-slot group, never straddles a batch
    int b = slot0 / SS;                 // magic-mul const divide
    int s = slot0 - b * SS;

    const int4 w = *reinterpret_cast<const int4*>(&winner[slot0]);
    const float4* r0 = reinterpret_cast<const float4*>(pf + (size_t)max(w.x, 0) * CC);
    const float4* r1 = reinterpret_cast<const float4*>(pf + (size_t)max(w.y, 0) * CC);
    const float4* r2 = reinterpret_cast<const float4*>(pf + (size_t)max(w.z, 0) * CC);
    const float4* r3 = reinterpret_cast<const float4*>(pf + (size_t)max(w.w, 0) * CC);
    const float s0 = (w.x >= 0) ? 1.0f : 0.0f;
    const float s1 = (w.y >= 0) ? 1.0f : 0.0f;
    const float s2 = (w.z >= 0) ? 1.0f : 0.0f;
    const float s3 = (w.w >= 0) ? 1.0f : 0.0f;

    float* obase = out + (size_t)b * (CC * SS) + s;
    #pragma unroll 4
    for (int q = 0; q < CC / 4; ++q) {
        float4 a0 = r0[q], a1 = r1[q], a2 = r2[q], a3 = r3[q];
        a0.x *= s0; a0.y *= s0; a0.z *= s0; a0.w *= s0;
        a1.x *= s1; a1.y *= s1; a1.z *= s1; a1.w *= s1;
        a2.x *= s2; a2.y *= s2; a2.z *= s2; a2.w *= s2;
        a3.x *= s3; a3.y *= s3; a3.z *= s3; a3.w *= s3;
        *reinterpret_cast<float4*>(obase + (size_t)(4 * q + 0) * SS) =
            make_float4(a0.x, a1.x, a2.x, a3.x);
        *reinterpret_cast<float4*>(obase + (size_t)(4 * q + 1) * SS) =
            make_float4(a0.y, a1.y, a2.y, a3.y);
        *reinterpret_cast<float4*>(obase + (size_t)(4 * q + 2) * SS) =
            make_float4(a0.z, a1.z, a2.z, a3.z);
        *reinterpret_cast<float4*>(obase + (size_t)(4 * q + 3) * SS) =
            make_float4(a0.w, a1.w, a2.w, a3.w);
    }
}

extern "C" void kernel_launch(void* const* d_in, const int* in_sizes, int n_in,
                              void* d_out, int out_size, void* d_ws, size_t ws_size,
                              hipStream_t stream) {
    const float* pf = (const float*)d_in[0];
    const int* cb   = (const int*)d_in[1];
    const int* cz   = (const int*)d_in[2];
    const int* cy   = (const int*)d_in[3];
    const int* cx   = (const int*)d_in[4];
    float* out      = (float*)d_out;

    const int P      = in_sizes[1];            // number of pillars
    const int nslots = out_size / CC;          // B * SS = 1,714,176

    int* winner = (int*)d_ws;                  // nslots ints = 6.86 MB
    hipMemsetAsync(winner, 0xFF, (size_t)nslots * sizeof(int), stream);  // -1

    winner_kernel<<<(P + 255) / 256, 256, 0, stream>>>(cb, cz, cy, cx, winner, P);

    const int ngroups = nslots >> 2;           // 428,544 four-slot groups
    scatter_kernel<<<(ngroups + 255) / 256, 256, 0, stream>>>(pf, winner, out, ngroups);
}

// Round 5
// 487.130 us; speedup vs baseline: 1.2789x; 1.1455x over previous
//
#include <hip/hip_runtime.h>

// PointPillarScatter, LDS-transposed scatter:
//   pass 1: winner[b*SS+s] = max p writing (b,s)  (last-write-wins, verified R1)
//   pass 2: block owns 1024 slots; winners in regs; 4 channel-group passes:
//           gather 64B row-chunks once (pf traffic stays compulsory ~32MB),
//           transpose via XOR-swizzled 64KB LDS, write each channel plane as a
//           4KB contiguous nontemporal run (439MB write-once stream skips L2).

#define NXx 432
#define NYy 496
#define SS  (NXx * NYy)   // 214272; SS % 4 == 0
#define CC  64
#define TS  1024          // slots per block; nslots % TS == 0 (1674 blocks)

typedef float f4 __attribute__((ext_vector_type(4)));

__global__ void winner_kernel(const int* __restrict__ cb,
                              const int* __restrict__ cz,
                              const int* __restrict__ cy,
                              const int* __restrict__ cx,
                              int* __restrict__ winner, int P) {
    int p = blockIdx.x * blockDim.x + threadIdx.x;
    if (p < P) {
        int slot = cb[p] * SS + cz[p] + cy[p] * NXx + cx[p];
        atomicMax(&winner[slot], p);
    }
}

__global__ __launch_bounds__(256)
void scatter_kernel(const float* __restrict__ pf,
                    const int* __restrict__ winner,
                    float* __restrict__ out) {
    __shared__ float lds[TS * 16];          // 64 KB: 1024 slots x 16 channels
    const int t = threadIdx.x;
    const int slot0 = blockIdx.x * TS;

    // Winners for my 4 strided slots, loaded once (coalesced).
    int w[4];
    #pragma unroll
    for (int k = 0; k < 4; ++k) w[k] = winner[slot0 + k * 256 + t];

    // Phase-2 store base: thread t owns global slots slot0+4t .. +3 (one batch,
    // since SS % 4 == 0). b is per-thread (tiles may straddle batches).
    const int gs = slot0 + 4 * t;
    const int b  = gs / SS;                 // magic-mul const divide
    const int s  = gs - b * SS;
    float* const obase = out + (size_t)(b * CC) * SS + s;

    for (int cg = 0; cg < 4; ++cg) {
        // ---- phase 1: gather 16-channel chunk of each winner row into LDS ----
        #pragma unroll
        for (int k = 0; k < 4; ++k) {
            const int sl = k * 256 + t;
            const int sw = (sl >> 2) & 15;  // XOR swizzle key
            float v[16];
            if (w[k] >= 0) {
                const f4* row = reinterpret_cast<const f4*>(
                    pf + (size_t)w[k] * CC + cg * 16);
                f4 a = row[0], bq = row[1], cq = row[2], dq = row[3];
                v[0]=a.x;  v[1]=a.y;  v[2]=a.z;  v[3]=a.w;
                v[4]=bq.x; v[5]=bq.y; v[6]=bq.z; v[7]=bq.w;
                v[8]=cq.x; v[9]=cq.y; v[10]=cq.z; v[11]=cq.w;
                v[12]=dq.x; v[13]=dq.y; v[14]=dq.z; v[15]=dq.w;
            } else {
                #pragma unroll
                for (int c = 0; c < 16; ++c) v[c] = 0.0f;
            }
            #pragma unroll
            for (int c = 0; c < 16; ++c)
                lds[sl * 16 + (c ^ sw)] = v[c];   // 2-way banks (free)
        }
        __syncthreads();

        // ---- phase 2: 16 channels x 1024 slots; float4 per thread/channel ----
        const int sw2 = t & 15;             // (4t+i)>>2 & 15 == t & 15
        #pragma unroll
        for (int c = 0; c < 16; ++c) {
            f4 o;
            o.x = lds[(4 * t + 0) * 16 + (c ^ sw2)];   // 4-way banks (1.58x)
            o.y = lds[(4 * t + 1) * 16 + (c ^ sw2)];
            o.z = lds[(4 * t + 2) * 16 + (c ^ sw2)];
            o.w = lds[(4 * t + 3) * 16 + (c ^ sw2)];
            __builtin_nontemporal_store(
                o, reinterpret_cast<f4*>(obase + (size_t)(cg * 16 + c) * SS));
        }
        __syncthreads();
    }
}

extern "C" void kernel_launch(void* const* d_in, const int* in_sizes, int n_in,
                              void* d_out, int out_size, void* d_ws, size_t ws_size,
                              hipStream_t stream) {
    const float* pf = (const float*)d_in[0];
    const int* cb   = (const int*)d_in[1];
    const int* cz   = (const int*)d_in[2];
    const int* cy   = (const int*)d_in[3];
    const int* cx   = (const int*)d_in[4];
    float* out      = (float*)d_out;

    const int P      = in_sizes[1];          // number of pillars
    const int nslots = out_size / CC;        // B * SS = 1,714,176 (TS-divisible)

    int* winner = (int*)d_ws;                // nslots ints = 6.86 MB
    hipMemsetAsync(winner, 0xFF, (size_t)nslots * sizeof(int), stream);  // -1

    winner_kernel<<<(P + 255) / 256, 256, 0, stream>>>(cb, cz, cy, cx, winner, P);

    scatter_kernel<<<nslots / TS, 256, 0, stream>>>(pf, winner, out);
}